// Round 5
// baseline (4467.532 us; speedup 1.0000x reference)
//
#include <hip/hip_runtime.h>
#include <hip/hip_bf16.h>

#define Bsz 128
#define Tsz 1024
#define Dsz 128
#define Hsz 512
#define NBLK 256
#define NXC 4    // x K-chunks (128/32)
#define NHC 16   // h K-chunks (512/32)

typedef __attribute__((ext_vector_type(8))) short short8;
typedef __attribute__((ext_vector_type(4))) float f4;
typedef unsigned long long u64;
typedef unsigned int u32;

#define TAGMASK 0xffff0000ffff0000ULL

__device__ __forceinline__ unsigned short bf16_rne(float f) {
  unsigned u = __builtin_bit_cast(unsigned, f);
  u += 0x7fffu + ((u >> 16) & 1u);
  return (unsigned short)(u >> 16);
}
__device__ __forceinline__ float sigmoid_(float v) { return 1.f / (1.f + __expf(-v)); }
__device__ __forceinline__ float tanh_(float v) {
  v = fminf(fmaxf(v, -15.f), 15.f);
  float e = __expf(2.f * v);
  return (e - 1.f) / (e + 1.f);
}
__device__ __forceinline__ short8 cvt8(f4 v0, f4 v1) {
  short8 a;
  a[0] = (short)bf16_rne(v0[0]); a[1] = (short)bf16_rne(v0[1]);
  a[2] = (short)bf16_rne(v0[2]); a[3] = (short)bf16_rne(v0[3]);
  a[4] = (short)bf16_rne(v1[0]); a[5] = (short)bf16_rne(v1[1]);
  a[6] = (short)bf16_rne(v1[2]); a[7] = (short)bf16_rne(v1[3]);
  return a;
}
__device__ __forceinline__ u32 untag2(u64 v) {   // two tagged cells -> bf16 pair
  return (u32)(v & 0xffffu) | ((u32)(v >> 16) & 0xffff0000u);
}

// Persistent LSTM v5: tag-fused h exchange (no flags, no vmcnt drain, no bar3).
//  - h cell stored as tagged u32: (t+1)<<16 | bf16(h). Dword stores are atomic
//    units; tag+data travel together, so any wider-store tearing is harmless.
//  - consumer polls the DATA until tag==t: flag-visible + poll + data-load
//    round trips collapse into one. Producer fire-and-forget agent stores.
//  - skew<=1 step (producer passes iter-t poll only after ALL peers stored
//    tag t), so parity double-buffer suffices; poison 0xAAAA is a stale tag.
//  - wave=gate mapping, LDS gate exchange, coalesced per-row tagged stores
//    (R2-proven); x tile in regs, x-MFMA before the poll (fills wait).
__global__ __launch_bounds__(256, 1) void lstm_persist(
    const float* __restrict__ x, const float* __restrict__ W_ih,
    const float* __restrict__ W_hh, const float* __restrict__ b_ih,
    const float* __restrict__ b_hh, const float* __restrict__ W_fc,
    const float* __restrict__ b_fc, float* __restrict__ out,
    u32* hb0, u32* hb1)
{
  const int bx = blockIdx.x;
  const int bt = bx & 7, ks = bx >> 3;     // 8 row-groups x 32 col-blocks
  const int b0 = bt << 4, k0 = ks << 4;
  const int tx = threadIdx.x;
  const int wave = tx >> 6, lane = tx & 63;
  const int m = lane & 15, quad = lane >> 4;
  const int k_l = tx & 15, b_l = tx >> 4;  // epilogue ownership: (b_l, k_l)

  __shared__ short8 A_h[NHC][64];      // 16 KB h fragments
  __shared__ f4 gates_lds[4][64];      // 4 KB per-gate D fragments
  __shared__ float fc_red[16][16];

  // ---- W fragments in registers (wave = gate) ----
  short8 wfrag[NXC + NHC];
  {
    const int j = wave * Hsz + k0 + m;   // W row = output column n
    #pragma unroll
    for (int kc = 0; kc < NXC + NHC; ++kc) {
      const int kk = kc * 32 + quad * 8;
      const float* src = (kk < Dsz) ? (W_ih + (size_t)j * Dsz + kk)
                                    : (W_hh + (size_t)j * Hsz + (kk - Dsz));
      const f4* sv = (const f4*)src;
      wfrag[kc] = cvt8(sv[0], sv[1]);
    }
  }
  float bias[4];
  #pragma unroll
  for (int g = 0; g < 4; ++g)
    bias[g] = b_ih[g * Hsz + k0 + k_l] + b_hh[g * Hsz + k0 + k_l];
  float c_reg = 0.f;

  // ---- pre-loop: x(0) into regs, zero A_h ----
  const float* xbase = x + (size_t)(b0 + m) * (Tsz * Dsz);
  short8 xa[NXC];
  #pragma unroll
  for (int kc = 0; kc < NXC; ++kc) {
    const f4* xv = (const f4*)(xbase + kc * 32 + quad * 8);
    xa[kc] = cvt8(xv[0], xv[1]);
  }
  {
    short8 z = {0, 0, 0, 0, 0, 0, 0, 0};
    #pragma unroll
    for (int q = 0; q < 4; ++q) A_h[wave * 4 + q][lane] = z;
  }

  for (int t = 0; t < Tsz; ++t) {
    u32* hnext = (t & 1) ? hb1 : hb0;                       // stores tag t+1
    const u64* hprev = (const u64*)((t & 1) ? hb0 : hb1);   // holds tag t

    // ---- x-part GEMM (no h dependence; overlaps the wait) ----
    f4 acc0 = {0.f, 0.f, 0.f, 0.f}, acc1 = {0.f, 0.f, 0.f, 0.f};
    acc0 = __builtin_amdgcn_mfma_f32_16x16x32_bf16(xa[0], wfrag[0], acc0, 0, 0, 0);
    acc1 = __builtin_amdgcn_mfma_f32_16x16x32_bf16(xa[1], wfrag[1], acc1, 0, 0, 0);
    acc0 = __builtin_amdgcn_mfma_f32_16x16x32_bf16(xa[2], wfrag[2], acc0, 0, 0, 0);
    acc1 = __builtin_amdgcn_mfma_f32_16x16x32_bf16(xa[3], wfrag[3], acc1, 0, 0, 0);

    // ---- prefetch x(t+1), in flight during the poll ----
    f4 q0, q1, q2, q3, q4, q5, q6, q7;
    if (t + 1 < Tsz) {
      const float* xp = xbase + (size_t)(t + 1) * Dsz + quad * 8;
      q0 = ((const f4*)(xp))[0];      q1 = ((const f4*)(xp))[1];
      q2 = ((const f4*)(xp + 32))[0]; q3 = ((const f4*)(xp + 32))[1];
      q4 = ((const f4*)(xp + 64))[0]; q5 = ((const f4*)(xp + 64))[1];
      q6 = ((const f4*)(xp + 96))[0]; q7 = ((const f4*)(xp + 96))[1];
    }

    if (t > 0) {
      const u64 want = ((u64)(u32)t << 48) | ((u64)(u32)t << 16);
      #pragma unroll
      for (int q = 0; q < 4; ++q) {
        const int hc = wave * 4 + q;
        const u64* p = hprev + (((size_t)(b0 + m) * Hsz + hc * 32 + quad * 8) >> 1);
        u64 v0 = __hip_atomic_load(p + 0, __ATOMIC_RELAXED, __HIP_MEMORY_SCOPE_AGENT);
        u64 v1 = __hip_atomic_load(p + 1, __ATOMIC_RELAXED, __HIP_MEMORY_SCOPE_AGENT);
        u64 v2 = __hip_atomic_load(p + 2, __ATOMIC_RELAXED, __HIP_MEMORY_SCOPE_AGENT);
        u64 v3 = __hip_atomic_load(p + 3, __ATOMIC_RELAXED, __HIP_MEMORY_SCOPE_AGENT);
        while ((v0 ^ want) & TAGMASK)
          v0 = __hip_atomic_load(p + 0, __ATOMIC_RELAXED, __HIP_MEMORY_SCOPE_AGENT);
        while ((v1 ^ want) & TAGMASK)
          v1 = __hip_atomic_load(p + 1, __ATOMIC_RELAXED, __HIP_MEMORY_SCOPE_AGENT);
        while ((v2 ^ want) & TAGMASK)
          v2 = __hip_atomic_load(p + 2, __ATOMIC_RELAXED, __HIP_MEMORY_SCOPE_AGENT);
        while ((v3 ^ want) & TAGMASK)
          v3 = __hip_atomic_load(p + 3, __ATOMIC_RELAXED, __HIP_MEMORY_SCOPE_AGENT);
        union { u32 w[4]; short8 s; } u;
        u.w[0] = untag2(v0); u.w[1] = untag2(v1);
        u.w[2] = untag2(v2); u.w[3] = untag2(v3);
        A_h[hc][lane] = u.s;
      }
    }
    __syncthreads();   // bar_h: A_h ready

    // ---- h-part GEMM: 16 x (ds_read_b128 + mfma) ----
    #pragma unroll
    for (int hc = 0; hc < NHC; hc += 2) {
      acc0 = __builtin_amdgcn_mfma_f32_16x16x32_bf16(A_h[hc][lane],     wfrag[NXC + hc],     acc0, 0, 0, 0);
      acc1 = __builtin_amdgcn_mfma_f32_16x16x32_bf16(A_h[hc + 1][lane], wfrag[NXC + hc + 1], acc1, 0, 0, 0);
    }
    gates_lds[wave][lane] = acc0 + acc1;   // D[b=quad*4+r][n=lane&15], gate=wave
    __syncthreads();   // bar_g

    { // ---- gate combine + state update + tagged store ----
      const int lp = ((b_l >> 2) << 4) + k_l;
      const int r = b_l & 3;
      float pi = gates_lds[0][lp][r] + bias[0];
      float pf = gates_lds[1][lp][r] + bias[1];
      float pg = gates_lds[2][lp][r] + bias[2];
      float po = gates_lds[3][lp][r] + bias[3];
      float iv = sigmoid_(pi), fv = sigmoid_(pf), ov = sigmoid_(po);
      float gv = tanh_(pg);
      c_reg = fv * c_reg + iv * gv;
      float hv = ov * tanh_(c_reg);
      u32 myw = ((u32)(t + 1) << 16) | (u32)bf16_rne(hv);
      u32 other = (u32)__shfl_xor((int)myw, 1);
      if ((k_l & 1) == 0) {   // u64 = cols (k_l, k_l+1), per-row coalesced
        u64 packed = (u64)myw | ((u64)other << 32);
        u64* p = (u64*)(hnext + (size_t)(b0 + b_l) * Hsz + k0 + k_l);
        __hip_atomic_store(p, packed, __ATOMIC_RELAXED, __HIP_MEMORY_SCOPE_AGENT);
      }
    }

    // ---- convert x(t+1) (off critical path; stores drain during next poll) ----
    if (t + 1 < Tsz) {
      xa[0] = cvt8(q0, q1); xa[1] = cvt8(q2, q3);
      xa[2] = cvt8(q4, q5); xa[3] = cvt8(q6, q7);
    }
    // no trailing barrier: bar_h(t+1) orders gates_lds reuse, tags order h.
  }

  // ---- final FC: out[b] = sigmoid(h_last . W_fc + b_fc), ks==0 blocks ----
  if (ks == 0) {
    const u64 want = ((u64)(u32)Tsz << 48) | ((u64)(u32)Tsz << 16);
    const u64* p = (const u64*)hb1 + (((size_t)(b0 + b_l) * Hsz + k_l * 32) >> 1);
    float partial = 0.f;
    #pragma unroll
    for (int q = 0; q < 16; ++q) {
      u64 v = __hip_atomic_load(p + q, __ATOMIC_RELAXED, __HIP_MEMORY_SCOPE_AGENT);
      while ((v ^ want) & TAGMASK)
        v = __hip_atomic_load(p + q, __ATOMIC_RELAXED, __HIP_MEMORY_SCOPE_AGENT);
      float h0 = __builtin_bit_cast(float, (u32)(v & 0xffffu) << 16);
      float h1 = __builtin_bit_cast(float, (u32)((v >> 32) & 0xffffu) << 16);
      partial += h0 * W_fc[k_l * 32 + 2 * q] + h1 * W_fc[k_l * 32 + 2 * q + 1];
    }
    fc_red[b_l][k_l] = partial;
    __syncthreads();
    if (k_l == 0) {
      float s = b_fc[0];
      #pragma unroll
      for (int e = 0; e < 16; ++e) s += fc_red[b_l][e];
      out[b0 + b_l] = sigmoid_(s);
    }
  }
}

extern "C" void kernel_launch(void* const* d_in, const int* in_sizes, int n_in,
                              void* d_out, int out_size, void* d_ws, size_t ws_size,
                              hipStream_t stream) {
  const float* x    = (const float*)d_in[0];
  const float* W_ih = (const float*)d_in[1];
  const float* W_hh = (const float*)d_in[2];
  const float* b_ih = (const float*)d_in[3];
  const float* b_hh = (const float*)d_in[4];
  const float* W_fc = (const float*)d_in[5];
  const float* b_fc = (const float*)d_in[6];
  float* out = (float*)d_out;
  char* ws = (char*)d_ws;
  u32* hb0 = (u32*)ws;                                   // 128x512 tagged u32
  u32* hb1 = (u32*)(ws + (size_t)Bsz * Hsz * 4);         // 256 KB each
  // no memset needed: 0xAAAA poison is a stale tag for all t in [1,1024]
  lstm_persist<<<NBLK, 256, 0, stream>>>(x, W_ih, W_hh, b_ih, b_hh, W_fc, b_fc,
                                         out, hb0, hb1);
}